// Round 1
// baseline (208.598 us; speedup 1.0000x reference)
//
#include <hip/hip_runtime.h>
#include <cstdint>
#include <cstddef>

#define PP 64
#define KK 8
#define HH 32
#define DD 2048
#define RR (PP*HH)        // 2048 center rows
#define FRN (PP*KK*HH)    // 16384 feature rows

typedef __attribute__((ext_vector_type(4))) float  f32x4;
typedef __attribute__((ext_vector_type(4))) float  float4v;
typedef __attribute__((ext_vector_type(8))) short  short8;
typedef __attribute__((ext_vector_type(8))) __bf16 bf16x8;

__device__ __forceinline__ unsigned short f2bf(float f) {
  unsigned int u = __builtin_bit_cast(unsigned int, f);
  u += 0x7fffu + ((u >> 16) & 1u);
  return (unsigned short)(u >> 16);
}

__device__ __forceinline__ void gload_lds16(const void* g, void* l) {
  __builtin_amdgcn_global_load_lds(
      (const __attribute__((address_space(1))) void*)g,
      (__attribute__((address_space(3))) void*)l, 16, 0, 0);
}

// K1: centers (mean over K), bf16 cast of centers, center row norms, feature row norms.
__global__ __launch_bounds__(256) void k_centers(const float* __restrict__ feat,
    unsigned short* __restrict__ cbf, float* __restrict__ cnorm,
    float* __restrict__ fnorm) {
  int row = blockIdx.x;            // p*32 + h
  int p = row >> 5, h = row & 31;
  int tid = threadIdx.x;
  int d0 = tid * 8;
  float c[8];
  float red[9];
  #pragma unroll
  for (int e = 0; e < 8; ++e) c[e] = 0.f;
  #pragma unroll
  for (int k = 0; k < KK; ++k) {
    const float* src = feat + ((size_t)((p*KK + k)*HH + h))*DD + d0;
    float4v f0 = *(const float4v*)src;
    float4v f1 = *(const float4v*)(src + 4);
    float s = 0.f;
    #pragma unroll
    for (int e = 0; e < 4; ++e) {
      c[e]   += f0[e];
      c[4+e] += f1[e];
      s += f0[e]*f0[e] + f1[e]*f1[e];
    }
    red[k] = s;
  }
  float csq = 0.f;
  #pragma unroll
  for (int e = 0; e < 8; ++e) { c[e] *= 0.125f; csq += c[e]*c[e]; }
  unsigned int pk[4];
  #pragma unroll
  for (int e = 0; e < 4; ++e)
    pk[e] = (unsigned int)f2bf(c[2*e]) | ((unsigned int)f2bf(c[2*e+1]) << 16);
  *(uint4*)(cbf + (size_t)row*DD + d0) = make_uint4(pk[0], pk[1], pk[2], pk[3]);
  red[8] = csq;

  __shared__ float lred[4][9];
  int lane = tid & 63, wv = tid >> 6;
  #pragma unroll
  for (int r = 0; r < 9; ++r) {
    float v = red[r];
    #pragma unroll
    for (int off = 32; off > 0; off >>= 1) v += __shfl_down(v, off, 64);
    if (lane == 0) lred[wv][r] = v;
  }
  __syncthreads();
  if (tid < 9) {
    float s = lred[0][tid] + lred[1][tid] + lred[2][tid] + lred[3][tid];
    if (tid < 8) fnorm[((size_t)(p*KK + tid))*HH + h] = s;
    else         cnorm[row] = s;
  }
}

// K2: inter Gram via bf16 MFMA, 128x128 tile, fused dist epilogue -> dm[pair][32][32]
__global__ __launch_bounds__(256) void k_inter(const unsigned short* __restrict__ cbf,
    const float* __restrict__ cnorm, float* __restrict__ dm) {
  __shared__ unsigned short Ab[128*32];
  __shared__ unsigned short Bb[128*32];
  int tid = threadIdx.x;
  int lane = tid & 63, w = tid >> 6;
  int tI = blockIdx.x >> 4, tJ = blockIdx.x & 15;
  int wrow = w >> 1, wcol = w & 1;
  int ln = lane & 15, kq = lane >> 4;
  f32x4 acc[4][4];
  #pragma unroll
  for (int a = 0; a < 4; ++a)
    #pragma unroll
    for (int b = 0; b < 4; ++b)
      #pragma unroll
      for (int e = 0; e < 4; ++e) acc[a][b][e] = 0.f;

  int srow = w*32 + (lane >> 2);
  int scol = (lane & 3)*8;
  const unsigned short* gA = cbf + (size_t)(tI*128 + srow)*DD + scol;
  const unsigned short* gB = cbf + (size_t)(tJ*128 + srow)*DD + scol;
  unsigned short* lA = &Ab[w*1024 + lane*8];
  unsigned short* lB = &Bb[w*1024 + lane*8];

  for (int k0 = 0; k0 < DD; k0 += 32) {
    gload_lds16(gA + k0,         lA);
    gload_lds16(gA + 16*DD + k0, lA + 512);
    gload_lds16(gB + k0,         lB);
    gload_lds16(gB + 16*DD + k0, lB + 512);
    __syncthreads();
    bf16x8 af[4], bfr[4];
    #pragma unroll
    for (int mt = 0; mt < 4; ++mt)
      af[mt] = *(const bf16x8*)&Ab[(wrow*64 + mt*16 + ln)*32 + kq*8];
    #pragma unroll
    for (int nt = 0; nt < 4; ++nt)
      bfr[nt] = *(const bf16x8*)&Bb[(wcol*64 + nt*16 + ln)*32 + kq*8];
    #pragma unroll
    for (int mt = 0; mt < 4; ++mt)
      #pragma unroll
      for (int nt = 0; nt < 4; ++nt)
        acc[mt][nt] = __builtin_amdgcn_mfma_f32_16x16x32_bf16(af[mt], bfr[nt], acc[mt][nt], 0, 0, 0);
    __syncthreads();
  }
  #pragma unroll
  for (int mt = 0; mt < 4; ++mt) {
    int rbase = tI*128 + wrow*64 + mt*16 + kq*4;
    #pragma unroll
    for (int nt = 0; nt < 4; ++nt) {
      int cc = tJ*128 + wcol*64 + nt*16 + ln;
      float nc = cnorm[cc];
      #pragma unroll
      for (int v = 0; v < 4; ++v) {
        int rr = rbase + v;
        float d2 = cnorm[rr] + nc - 2.f*acc[mt][nt][v];
        float t = tanhf(0.5f*sqrtf(fmaxf(d2, 1e-12f)));
        int a = rr >> 5, b = cc >> 5;
        dm[(((size_t)a*64 + b) << 10) + ((size_t)(rr & 31) << 5) + (cc & 31)] = t;
      }
    }
  }
}

// K3: intra distances: centers[p] (32 rows) vs feats[p] (256 rows), direct-from-global MFMA.
__global__ __launch_bounds__(256) void k_intra(const float* __restrict__ feat,
    const unsigned short* __restrict__ cbf, const float* __restrict__ cnorm,
    const float* __restrict__ fnorm, float* __restrict__ dm) {
  int p = blockIdx.x;
  int tid = threadIdx.x, lane = tid & 63, w = tid >> 6;
  int ln = lane & 15, kq = lane >> 4;
  f32x4 acc[2][4];
  #pragma unroll
  for (int a = 0; a < 2; ++a)
    #pragma unroll
    for (int b = 0; b < 4; ++b)
      #pragma unroll
      for (int e = 0; e < 4; ++e) acc[a][b][e] = 0.f;

  const unsigned short* ga = cbf + (size_t)(p*32 + ln)*DD + kq*8;
  const float* gb = feat + (size_t)(p*256 + w*64 + ln)*DD + kq*8;

  for (int k0 = 0; k0 < DD; k0 += 32) {
    bf16x8 af[2];
    #pragma unroll
    for (int mt = 0; mt < 2; ++mt)
      af[mt] = *(const bf16x8*)(ga + (size_t)mt*16*DD + k0);
    #pragma unroll
    for (int nt = 0; nt < 4; ++nt) {
      const float* s = gb + (size_t)nt*16*DD + k0;
      float4v f0 = *(const float4v*)s;
      float4v f1 = *(const float4v*)(s + 4);
      short8 bs;
      #pragma unroll
      for (int e = 0; e < 4; ++e) {
        bs[e]   = (short)f2bf(f0[e]);
        bs[4+e] = (short)f2bf(f1[e]);
      }
      bf16x8 bv = __builtin_bit_cast(bf16x8, bs);
      #pragma unroll
      for (int mt = 0; mt < 2; ++mt)
        acc[mt][nt] = __builtin_amdgcn_mfma_f32_16x16x32_bf16(af[mt], bv, acc[mt][nt], 0, 0, 0);
    }
  }
  #pragma unroll
  for (int mt = 0; mt < 2; ++mt) {
    #pragma unroll
    for (int nt = 0; nt < 4; ++nt) {
      int cl = w*64 + nt*16 + ln;          // 0..255 (k*32 + j)
      float nf = fnorm[(size_t)p*256 + cl];
      #pragma unroll
      for (int v = 0; v < 4; ++v) {
        int i = mt*16 + kq*4 + v;          // center stripe 0..31
        float d2 = cnorm[p*32 + i] + nf - 2.f*acc[mt][nt][v];
        float t = tanhf(0.5f*sqrtf(fmaxf(d2, 1e-12f)));
        int k = cl >> 5, j = cl & 31;
        dm[((size_t)(p*8 + k) << 10) + ((size_t)i << 5) + j] = t;
      }
    }
  }
}

// K4/K5: anti-diagonal wavefront DP. 32 lanes per pair, 8 pairs per block.
__global__ __launch_bounds__(256) void k_dp(const float* __restrict__ dm,
                                            float* __restrict__ out) {
  __shared__ float tile[8*1024];
  int t = threadIdx.x;
  size_t base = (size_t)blockIdx.x * 8 * 1024;
  const float4v* src = (const float4v*)(dm + base);
  float4v* dst = (float4v*)tile;
  #pragma unroll
  for (int c2 = 0; c2 < 8; ++c2) dst[c2*256 + t] = src[c2*256 + t];
  __syncthreads();
  const float INF = __builtin_inff();
  int j  = t & 31;
  int pl = t >> 5;
  const float* mt = &tile[pl << 10];
  float A = INF;
  for (int d = 0; d < 63; ++d) {
    float left = __shfl_up(A, 1, 32);
    if (j == 0) left = INF;
    int i = d - j;
    int ii = i < 0 ? 0 : (i > 31 ? 31 : i);
    float dv = mt[(ii << 5) + j];
    float up = (i == 0) ? (j == 0 ? 0.f : INF) : A;
    A = (i >= 0 && i < 32) ? (fminf(up, left) + dv) : INF;
  }
  if (j == 31) out[(size_t)blockIdx.x*8 + pl] = A;
}

// K6: reductions + loss. out = [loss, intra_max[64], inter_min[64]]
__global__ __launch_bounds__(64) void k_final(const float* __restrict__ inter_full,
    const float* __restrict__ intra_pk, float* __restrict__ out) {
  int p = threadIdx.x;  // 0..63
  const float INF = __builtin_inff();
  float mn = INF;
  #pragma unroll 8
  for (int b = 0; b < 64; ++b)
    if (b != p) mn = fminf(mn, inter_full[p*64 + b]);
  float mx = -INF;
  #pragma unroll
  for (int k = 0; k < 8; ++k) mx = fmaxf(mx, intra_pk[p*8 + k]);
  out[1 + p]  = mx;
  out[65 + p] = mn;
  float v = fmaxf(mx - mn + 10.0f, 0.0f);
  #pragma unroll
  for (int off = 32; off > 0; off >>= 1) v += __shfl_down(v, off, 64);
  if (p == 0) out[0] = v * (1.0f/64.0f);
}

extern "C" void kernel_launch(void* const* d_in, const int* in_sizes, int n_in,
                              void* d_out, int out_size, void* d_ws, size_t ws_size,
                              hipStream_t stream) {
  const float* feat = (const float*)d_in[0];
  float* out = (float*)d_out;
  char* w = (char*)d_ws;
  // workspace layout (bytes)
  unsigned short* cbf      = (unsigned short*)w;            // 2048*2048*2 = 8,388,608
  float* cnorm             = (float*)(w + 8388608);         // 2048*4
  float* fnorm             = (float*)(w + 8396800);         // 16384*4
  float* dm_inter          = (float*)(w + 8462336);         // 4096*1024*4 = 16,777,216
  float* dm_intra          = (float*)(w + 25239552);        // 512*1024*4  =  2,097,152
  float* inter_full        = (float*)(w + 27336704);        // 4096*4
  float* intra_pk          = (float*)(w + 27353088);        // 512*4
  // total 27,355,136 bytes

  k_centers<<<RR, 256, 0, stream>>>(feat, cbf, cnorm, fnorm);
  k_inter<<<256, 256, 0, stream>>>(cbf, cnorm, dm_inter);
  k_intra<<<PP, 256, 0, stream>>>(feat, cbf, cnorm, fnorm, dm_intra);
  k_dp<<<512, 256, 0, stream>>>(dm_inter, inter_full);
  k_dp<<<64, 256, 0, stream>>>(dm_intra, intra_pk);
  k_final<<<1, 64, 0, stream>>>(inter_full, intra_pk, out);
}

// Round 2
// 144.105 us; speedup vs baseline: 1.4475x; 1.4475x over previous
//
#include <hip/hip_runtime.h>
#include <cstdint>
#include <cstddef>

#define PP 64
#define KK 8
#define HH 32
#define DD 2048
#define RR (PP*HH)        // 2048 center rows

typedef __attribute__((ext_vector_type(4))) float  f32x4;
typedef __attribute__((ext_vector_type(4))) float  float4v;
typedef __attribute__((ext_vector_type(8))) short  short8;
typedef __attribute__((ext_vector_type(8))) __bf16 bf16x8;

__device__ __forceinline__ unsigned short f2bf(float f) {
  unsigned int u = __builtin_bit_cast(unsigned int, f);
  u += 0x7fffu + ((u >> 16) & 1u);
  return (unsigned short)(u >> 16);
}

__device__ __forceinline__ void gload_lds16(const void* g, void* l) {
  __builtin_amdgcn_global_load_lds(
      (const __attribute__((address_space(1))) void*)g,
      (__attribute__((address_space(3))) void*)l, 16, 0, 0);
}

// K1: centers (mean over K), bf16 cast of centers, center row norms, feature row norms.
__global__ __launch_bounds__(256) void k_centers(const float* __restrict__ feat,
    unsigned short* __restrict__ cbf, float* __restrict__ cnorm,
    float* __restrict__ fnorm) {
  int row = blockIdx.x;            // p*32 + h
  int p = row >> 5, h = row & 31;
  int tid = threadIdx.x;
  int d0 = tid * 8;
  float c[8];
  float red[9];
  #pragma unroll
  for (int e = 0; e < 8; ++e) c[e] = 0.f;
  #pragma unroll
  for (int k = 0; k < KK; ++k) {
    const float* src = feat + ((size_t)((p*KK + k)*HH + h))*DD + d0;
    float4v f0 = *(const float4v*)src;
    float4v f1 = *(const float4v*)(src + 4);
    float s = 0.f;
    #pragma unroll
    for (int e = 0; e < 4; ++e) {
      c[e]   += f0[e];
      c[4+e] += f1[e];
      s += f0[e]*f0[e] + f1[e]*f1[e];
    }
    red[k] = s;
  }
  float csq = 0.f;
  #pragma unroll
  for (int e = 0; e < 8; ++e) { c[e] *= 0.125f; csq += c[e]*c[e]; }
  unsigned int pk[4];
  #pragma unroll
  for (int e = 0; e < 4; ++e)
    pk[e] = (unsigned int)f2bf(c[2*e]) | ((unsigned int)f2bf(c[2*e+1]) << 16);
  *(uint4*)(cbf + (size_t)row*DD + d0) = make_uint4(pk[0], pk[1], pk[2], pk[3]);
  red[8] = csq;

  __shared__ float lred[4][9];
  int lane = tid & 63, wv = tid >> 6;
  #pragma unroll
  for (int r = 0; r < 9; ++r) {
    float v = red[r];
    #pragma unroll
    for (int off = 32; off > 0; off >>= 1) v += __shfl_down(v, off, 64);
    if (lane == 0) lred[wv][r] = v;
  }
  __syncthreads();
  if (tid < 9) {
    float s = lred[0][tid] + lred[1][tid] + lred[2][tid] + lred[3][tid];
    if (tid < 8) fnorm[((size_t)(p*KK + tid))*HH + h] = s;
    else         cnorm[row] = s;
  }
}

// K2: inter Gram via bf16 MFMA. 128x128 tile, 8 waves = 4 quadrants x 2 K-halves,
// BK=64, XOR-swizzled LDS (chunk ^= row&7), LDS reduce across K-halves,
// fused dist epilogue -> dm[pair][32][32].
__global__ __launch_bounds__(512) void k_inter(const unsigned short* __restrict__ cbf,
    const float* __restrict__ cnorm, float* __restrict__ dm) {
  __shared__ unsigned short Ab[128*64];   // 16 KB
  __shared__ unsigned short Bb[128*64];   // 16 KB
  int tid = threadIdx.x;
  int lane = tid & 63, w = tid >> 6;       // 8 waves
  int tI = blockIdx.x >> 4, tJ = blockIdx.x & 15;
  int q  = w & 3;                          // quadrant
  int kh = w >> 2;                         // K-half (0/1)
  int wrow = q >> 1, wcol = q & 1;
  int ln = lane & 15, kq = lane >> 4;
  f32x4 acc[4][4];
  #pragma unroll
  for (int a = 0; a < 4; ++a)
    #pragma unroll
    for (int b = 0; b < 4; ++b)
      #pragma unroll
      for (int e = 0; e < 4; ++e) acc[a][b][e] = 0.f;

  // staging geometry: wave w stages rows [w*16, w*16+16) via 2 gload_lds16
  int sr = (lane >> 3);                    // 0..7 within 8-row group
  int sc = lane & 7;                       // physical 16B chunk 0..7
  int jch0 = sc ^ sr;                      // logical chunk (row&7 == sr for both halves)
  const unsigned short* gA0 = cbf + (size_t)(tI*128 + w*16 + sr)*DD + jch0*8;
  const unsigned short* gB0 = cbf + (size_t)(tJ*128 + w*16 + sr)*DD + jch0*8;
  unsigned short* lA = &Ab[w*16*64 + lane*8];
  unsigned short* lB = &Bb[w*16*64 + lane*8];

  // fragment read addresses (element offsets), phys chunk = (kh*4+kq) ^ (ln&7)
  int phys = (kh*4 + kq) ^ (ln & 7);
  int aoff[4], boff[4];
  #pragma unroll
  for (int mt = 0; mt < 4; ++mt) {
    aoff[mt] = (wrow*64 + mt*16 + ln)*64 + phys*8;
    boff[mt] = (wcol*64 + mt*16 + ln)*64 + phys*8;
  }

  for (int k0 = 0; k0 < DD; k0 += 64) {
    gload_lds16(gA0 + k0,        lA);
    gload_lds16(gA0 + 8*DD + k0, lA + 512);
    gload_lds16(gB0 + k0,        lB);
    gload_lds16(gB0 + 8*DD + k0, lB + 512);
    __syncthreads();
    bf16x8 af[4], bfr[4];
    #pragma unroll
    for (int mt = 0; mt < 4; ++mt) {
      af[mt]  = *(const bf16x8*)&Ab[aoff[mt]];
      bfr[mt] = *(const bf16x8*)&Bb[boff[mt]];
    }
    #pragma unroll
    for (int mt = 0; mt < 4; ++mt)
      #pragma unroll
      for (int nt = 0; nt < 4; ++nt)
        acc[mt][nt] = __builtin_amdgcn_mfma_f32_16x16x32_bf16(af[mt], bfr[nt], acc[mt][nt], 0, 0, 0);
    __syncthreads();
  }

  // reduce K-half partials: waves 4..7 -> waves 0..3 (4 rounds through LDS)
  float* fbuf = (float*)Ab;                // 16 KB needed per round
  #pragma unroll
  for (int mt = 0; mt < 4; ++mt) {
    __syncthreads();
    if (w >= 4) {
      float* fb = fbuf + (w - 4)*1024 + lane*16;
      #pragma unroll
      for (int nt = 0; nt < 4; ++nt) *(f32x4*)(fb + nt*4) = acc[mt][nt];
    }
    __syncthreads();
    if (w < 4) {
      const float* fb = fbuf + w*1024 + lane*16;
      #pragma unroll
      for (int nt = 0; nt < 4; ++nt) acc[mt][nt] += *(const f32x4*)(fb + nt*4);
    }
  }

  if (w < 4) {
    #pragma unroll
    for (int mt = 0; mt < 4; ++mt) {
      int rbase = tI*128 + wrow*64 + mt*16 + kq*4;
      #pragma unroll
      for (int nt = 0; nt < 4; ++nt) {
        int cc = tJ*128 + wcol*64 + nt*16 + ln;
        float nc = cnorm[cc];
        #pragma unroll
        for (int v = 0; v < 4; ++v) {
          int rr = rbase + v;
          float d2 = cnorm[rr] + nc - 2.f*acc[mt][nt][v];
          float t = tanhf(0.5f*sqrtf(fmaxf(d2, 1e-12f)));
          int a = rr >> 5, b = cc >> 5;
          dm[(((size_t)a*64 + b) << 10) + ((size_t)(rr & 31) << 5) + (cc & 31)] = t;
        }
      }
    }
  }
}

// K3: intra distances. grid = P*8 blocks, 4 waves each, one 16x16 MFMA tile per wave,
// K=2048 streamed direct from global (centers bf16, features fp32 -> truncated bf16).
__global__ __launch_bounds__(256) void k_intra(const float* __restrict__ feat,
    const unsigned short* __restrict__ cbf, const float* __restrict__ cnorm,
    const float* __restrict__ fnorm, float* __restrict__ dm) {
  int p  = blockIdx.x >> 3;
  int jb = blockIdx.x & 7;                 // 32-feature-row block
  int tid = threadIdx.x, lane = tid & 63, w = tid >> 6;
  int mi = w >> 1, ni = w & 1;
  int ln = lane & 15, kq = lane >> 4;
  f32x4 acc;
  #pragma unroll
  for (int e = 0; e < 4; ++e) acc[e] = 0.f;

  const unsigned short* ga = cbf + (size_t)(p*32 + mi*16 + ln)*DD + kq*8;
  const float* gb = feat + (size_t)(p*256 + jb*32 + ni*16 + ln)*DD + kq*8;

  for (int k0 = 0; k0 < DD; k0 += 32) {
    bf16x8 af = *(const bf16x8*)(ga + k0);
    float4v f0 = *(const float4v*)(gb + k0);
    float4v f1 = *(const float4v*)(gb + k0 + 4);
    unsigned int pk[4];
    #pragma unroll
    for (int e = 0; e < 2; ++e) {
      unsigned int a0 = __builtin_bit_cast(unsigned int, f0[2*e]);
      unsigned int a1 = __builtin_bit_cast(unsigned int, f0[2*e+1]);
      unsigned int b0 = __builtin_bit_cast(unsigned int, f1[2*e]);
      unsigned int b1 = __builtin_bit_cast(unsigned int, f1[2*e+1]);
      pk[e]   = (a0 >> 16) | (a1 & 0xffff0000u);   // truncated bf16 pair
      pk[2+e] = (b0 >> 16) | (b1 & 0xffff0000u);
    }
    bf16x8 bv = __builtin_bit_cast(bf16x8, pk);
    acc = __builtin_amdgcn_mfma_f32_16x16x32_bf16(af, bv, acc, 0, 0, 0);
  }

  int cl = jb*32 + ni*16 + ln;             // feature index within class: k*32 + j
  float nf = fnorm[(size_t)p*256 + cl];
  int kidx = cl >> 5, jj = cl & 31;
  #pragma unroll
  for (int v = 0; v < 4; ++v) {
    int i = mi*16 + kq*4 + v;              // center stripe
    float d2 = cnorm[p*32 + i] + nf - 2.f*acc[v];
    float t = tanhf(0.5f*sqrtf(fmaxf(d2, 1e-12f)));
    dm[((size_t)(p*8 + kidx) << 10) + ((size_t)i << 5) + jj] = t;
  }
}

// K4/K5: anti-diagonal wavefront DP. 32 lanes per pair, 8 pairs per block.
__global__ __launch_bounds__(256) void k_dp(const float* __restrict__ dm,
                                            float* __restrict__ out) {
  __shared__ float tile[8*1024];
  int t = threadIdx.x;
  size_t base = (size_t)blockIdx.x * 8 * 1024;
  const float4v* src = (const float4v*)(dm + base);
  float4v* dst = (float4v*)tile;
  #pragma unroll
  for (int c2 = 0; c2 < 8; ++c2) dst[c2*256 + t] = src[c2*256 + t];
  __syncthreads();
  const float INF = __builtin_inff();
  int j  = t & 31;
  int pl = t >> 5;
  const float* mt = &tile[pl << 10];
  float A = INF;
  for (int d = 0; d < 63; ++d) {
    float left = __shfl_up(A, 1, 32);
    if (j == 0) left = INF;
    int i = d - j;
    int ii = i < 0 ? 0 : (i > 31 ? 31 : i);
    float dv = mt[(ii << 5) + j];
    float up = (i == 0) ? (j == 0 ? 0.f : INF) : A;
    A = (i >= 0 && i < 32) ? (fminf(up, left) + dv) : INF;
  }
  if (j == 31) out[(size_t)blockIdx.x*8 + pl] = A;
}

// K6: reductions + loss. out = [loss, intra_max[64], inter_min[64]]
__global__ __launch_bounds__(64) void k_final(const float* __restrict__ inter_full,
    const float* __restrict__ intra_pk, float* __restrict__ out) {
  int p = threadIdx.x;  // 0..63
  const float INF = __builtin_inff();
  float mn = INF;
  #pragma unroll 8
  for (int b = 0; b < 64; ++b)
    if (b != p) mn = fminf(mn, inter_full[p*64 + b]);
  float mx = -INF;
  #pragma unroll
  for (int k = 0; k < 8; ++k) mx = fmaxf(mx, intra_pk[p*8 + k]);
  out[1 + p]  = mx;
  out[65 + p] = mn;
  float v = fmaxf(mx - mn + 10.0f, 0.0f);
  #pragma unroll
  for (int off = 32; off > 0; off >>= 1) v += __shfl_down(v, off, 64);
  if (p == 0) out[0] = v * (1.0f/64.0f);
}

extern "C" void kernel_launch(void* const* d_in, const int* in_sizes, int n_in,
                              void* d_out, int out_size, void* d_ws, size_t ws_size,
                              hipStream_t stream) {
  const float* feat = (const float*)d_in[0];
  float* out = (float*)d_out;
  char* w = (char*)d_ws;
  // workspace layout (bytes)
  unsigned short* cbf      = (unsigned short*)w;            // 2048*2048*2 = 8,388,608
  float* cnorm             = (float*)(w + 8388608);         // 2048*4
  float* fnorm             = (float*)(w + 8396800);         // 16384*4
  float* dm_inter          = (float*)(w + 8462336);         // 4096*1024*4 = 16,777,216
  float* dm_intra          = (float*)(w + 25239552);        // 512*1024*4  =  2,097,152
  float* inter_full        = (float*)(w + 27336704);        // 4096*4
  float* intra_pk          = (float*)(w + 27353088);        // 512*4
  // total 27,355,136 bytes

  k_centers<<<RR, 256, 0, stream>>>(feat, cbf, cnorm, fnorm);
  k_inter<<<256, 512, 0, stream>>>(cbf, cnorm, dm_inter);
  k_intra<<<PP*8, 256, 0, stream>>>(feat, cbf, cnorm, fnorm, dm_intra);
  k_dp<<<512, 256, 0, stream>>>(dm_inter, inter_full);
  k_dp<<<64, 256, 0, stream>>>(dm_intra, intra_pk);
  k_final<<<1, 64, 0, stream>>>(inter_full, intra_pk, out);
}

// Round 3
// 138.631 us; speedup vs baseline: 1.5047x; 1.0395x over previous
//
#include <hip/hip_runtime.h>
#include <cstdint>
#include <cstddef>

#define PP 64
#define KK 8
#define HH 32
#define DD 2048
#define RR (PP*HH)        // 2048 center rows

typedef __attribute__((ext_vector_type(4))) float  f32x4;
typedef __attribute__((ext_vector_type(4))) float  float4v;
typedef __attribute__((ext_vector_type(8))) short  short8;
typedef __attribute__((ext_vector_type(8))) __bf16 bf16x8;

__device__ __forceinline__ unsigned short f2bf(float f) {
  unsigned int u = __builtin_bit_cast(unsigned int, f);
  u += 0x7fffu + ((u >> 16) & 1u);
  return (unsigned short)(u >> 16);
}

__device__ __forceinline__ void gload_lds16(const void* g, void* l) {
  __builtin_amdgcn_global_load_lds(
      (const __attribute__((address_space(1))) void*)g,
      (__attribute__((address_space(3))) void*)l, 16, 0, 0);
}

// K1: centers (mean over K), bf16 cast of centers, center row norms, feature row norms.
__global__ __launch_bounds__(256) void k_centers(const float* __restrict__ feat,
    unsigned short* __restrict__ cbf, float* __restrict__ cnorm,
    float* __restrict__ fnorm) {
  int row = blockIdx.x;            // p*32 + h
  int p = row >> 5, h = row & 31;
  int tid = threadIdx.x;
  int d0 = tid * 8;
  float c[8];
  float red[9];
  #pragma unroll
  for (int e = 0; e < 8; ++e) c[e] = 0.f;
  #pragma unroll
  for (int k = 0; k < KK; ++k) {
    const float* src = feat + ((size_t)((p*KK + k)*HH + h))*DD + d0;
    float4v f0 = *(const float4v*)src;
    float4v f1 = *(const float4v*)(src + 4);
    float s = 0.f;
    #pragma unroll
    for (int e = 0; e < 4; ++e) {
      c[e]   += f0[e];
      c[4+e] += f1[e];
      s += f0[e]*f0[e] + f1[e]*f1[e];
    }
    red[k] = s;
  }
  float csq = 0.f;
  #pragma unroll
  for (int e = 0; e < 8; ++e) { c[e] *= 0.125f; csq += c[e]*c[e]; }
  unsigned int pk[4];
  #pragma unroll
  for (int e = 0; e < 4; ++e)
    pk[e] = (unsigned int)f2bf(c[2*e]) | ((unsigned int)f2bf(c[2*e+1]) << 16);
  *(uint4*)(cbf + (size_t)row*DD + d0) = make_uint4(pk[0], pk[1], pk[2], pk[3]);
  red[8] = csq;

  __shared__ float lred[4][9];
  int lane = tid & 63, wv = tid >> 6;
  #pragma unroll
  for (int r = 0; r < 9; ++r) {
    float v = red[r];
    #pragma unroll
    for (int off = 32; off > 0; off >>= 1) v += __shfl_down(v, off, 64);
    if (lane == 0) lred[wv][r] = v;
  }
  __syncthreads();
  if (tid < 9) {
    float s = lred[0][tid] + lred[1][tid] + lred[2][tid] + lred[3][tid];
    if (tid < 8) fnorm[((size_t)(p*KK + tid))*HH + h] = s;
    else         cnorm[row] = s;
  }
}

// K2: inter Gram via bf16 MFMA. 128x128 tile, 8 waves = 4 quadrants x 2 K-halves,
// BK=64, XOR-swizzled LDS (chunk ^= row&7), LDS reduce across K-halves,
// fused dist epilogue -> dm[pair][32][32].
__global__ __launch_bounds__(512) void k_inter(const unsigned short* __restrict__ cbf,
    const float* __restrict__ cnorm, float* __restrict__ dm) {
  __shared__ unsigned short Ab[128*64];   // 16 KB
  __shared__ unsigned short Bb[128*64];   // 16 KB
  int tid = threadIdx.x;
  int lane = tid & 63, w = tid >> 6;       // 8 waves
  int tI = blockIdx.x >> 4, tJ = blockIdx.x & 15;
  int q  = w & 3;                          // quadrant
  int kh = w >> 2;                         // K-half (0/1)
  int wrow = q >> 1, wcol = q & 1;
  int ln = lane & 15, kq = lane >> 4;
  f32x4 acc[4][4];
  #pragma unroll
  for (int a = 0; a < 4; ++a)
    #pragma unroll
    for (int b = 0; b < 4; ++b)
      #pragma unroll
      for (int e = 0; e < 4; ++e) acc[a][b][e] = 0.f;

  // staging geometry: wave w stages rows [w*16, w*16+16) via 2 gload_lds16
  int sr = (lane >> 3);                    // 0..7 within 8-row group
  int sc = lane & 7;                       // physical 16B chunk 0..7
  int jch0 = sc ^ sr;                      // logical chunk (row&7 == sr for both halves)
  const unsigned short* gA0 = cbf + (size_t)(tI*128 + w*16 + sr)*DD + jch0*8;
  const unsigned short* gB0 = cbf + (size_t)(tJ*128 + w*16 + sr)*DD + jch0*8;
  unsigned short* lA = &Ab[w*16*64 + lane*8];
  unsigned short* lB = &Bb[w*16*64 + lane*8];

  // fragment read addresses (element offsets), phys chunk = (kh*4+kq) ^ (ln&7)
  int phys = (kh*4 + kq) ^ (ln & 7);
  int aoff[4], boff[4];
  #pragma unroll
  for (int mt = 0; mt < 4; ++mt) {
    aoff[mt] = (wrow*64 + mt*16 + ln)*64 + phys*8;
    boff[mt] = (wcol*64 + mt*16 + ln)*64 + phys*8;
  }

  for (int k0 = 0; k0 < DD; k0 += 64) {
    gload_lds16(gA0 + k0,        lA);
    gload_lds16(gA0 + 8*DD + k0, lA + 512);
    gload_lds16(gB0 + k0,        lB);
    gload_lds16(gB0 + 8*DD + k0, lB + 512);
    __syncthreads();
    bf16x8 af[4], bfr[4];
    #pragma unroll
    for (int mt = 0; mt < 4; ++mt) {
      af[mt]  = *(const bf16x8*)&Ab[aoff[mt]];
      bfr[mt] = *(const bf16x8*)&Bb[boff[mt]];
    }
    #pragma unroll
    for (int mt = 0; mt < 4; ++mt)
      #pragma unroll
      for (int nt = 0; nt < 4; ++nt)
        acc[mt][nt] = __builtin_amdgcn_mfma_f32_16x16x32_bf16(af[mt], bfr[nt], acc[mt][nt], 0, 0, 0);
    __syncthreads();
  }

  // reduce K-half partials: waves 4..7 -> waves 0..3 (4 rounds through LDS)
  float* fbuf = (float*)Ab;                // 16 KB needed per round
  #pragma unroll
  for (int mt = 0; mt < 4; ++mt) {
    __syncthreads();
    if (w >= 4) {
      float* fb = fbuf + (w - 4)*1024 + lane*16;
      #pragma unroll
      for (int nt = 0; nt < 4; ++nt) *(f32x4*)(fb + nt*4) = acc[mt][nt];
    }
    __syncthreads();
    if (w < 4) {
      const float* fb = fbuf + w*1024 + lane*16;
      #pragma unroll
      for (int nt = 0; nt < 4; ++nt) acc[mt][nt] += *(const f32x4*)(fb + nt*4);
    }
  }

  if (w < 4) {
    #pragma unroll
    for (int mt = 0; mt < 4; ++mt) {
      int rbase = tI*128 + wrow*64 + mt*16 + kq*4;
      #pragma unroll
      for (int nt = 0; nt < 4; ++nt) {
        int cc = tJ*128 + wcol*64 + nt*16 + ln;
        float nc = cnorm[cc];
        #pragma unroll
        for (int v = 0; v < 4; ++v) {
          int rr = rbase + v;
          float d2 = cnorm[rr] + nc - 2.f*acc[mt][nt][v];
          float t = tanhf(0.5f*sqrtf(fmaxf(d2, 1e-12f)));
          int a = rr >> 5, b = cc >> 5;
          dm[(((size_t)a*64 + b) << 10) + ((size_t)(rr & 31) << 5) + (cc & 31)] = t;
        }
      }
    }
  }
}

// K3: intra distances. grid = P*8 blocks, 4 waves each, one 16x16 MFMA tile per wave.
// K streamed direct from global, manually unrolled x4 (12 loads in flight per wave).
__global__ __launch_bounds__(256) void k_intra(const float* __restrict__ feat,
    const unsigned short* __restrict__ cbf, const float* __restrict__ cnorm,
    const float* __restrict__ fnorm, float* __restrict__ dm) {
  int p  = blockIdx.x >> 3;
  int jb = blockIdx.x & 7;                 // 32-feature-row block
  int tid = threadIdx.x, lane = tid & 63, w = tid >> 6;
  int mi = w >> 1, ni = w & 1;
  int ln = lane & 15, kq = lane >> 4;
  f32x4 acc;
  #pragma unroll
  for (int e = 0; e < 4; ++e) acc[e] = 0.f;

  const unsigned short* ga = cbf + (size_t)(p*32 + mi*16 + ln)*DD + kq*8;
  const float* gb = feat + (size_t)(p*256 + jb*32 + ni*16 + ln)*DD + kq*8;

  for (int k0 = 0; k0 < DD; k0 += 128) {
    bf16x8 af[4];
    float4v f0[4], f1[4];
    #pragma unroll
    for (int u = 0; u < 4; ++u) {
      af[u] = *(const bf16x8*)(ga + k0 + u*32);
      f0[u] = *(const float4v*)(gb + k0 + u*32);
      f1[u] = *(const float4v*)(gb + k0 + u*32 + 4);
    }
    #pragma unroll
    for (int u = 0; u < 4; ++u) {
      unsigned int pk[4];
      #pragma unroll
      for (int e = 0; e < 2; ++e) {
        unsigned int a0 = __builtin_bit_cast(unsigned int, f0[u][2*e]);
        unsigned int a1 = __builtin_bit_cast(unsigned int, f0[u][2*e+1]);
        unsigned int b0 = __builtin_bit_cast(unsigned int, f1[u][2*e]);
        unsigned int b1 = __builtin_bit_cast(unsigned int, f1[u][2*e+1]);
        pk[e]   = (a0 >> 16) | (a1 & 0xffff0000u);   // truncated bf16 pair
        pk[2+e] = (b0 >> 16) | (b1 & 0xffff0000u);
      }
      bf16x8 bv = __builtin_bit_cast(bf16x8, pk);
      acc = __builtin_amdgcn_mfma_f32_16x16x32_bf16(af[u], bv, acc, 0, 0, 0);
    }
  }

  int cl = jb*32 + ni*16 + ln;             // feature index within class: k*32 + j
  float nf = fnorm[(size_t)p*256 + cl];
  int kidx = cl >> 5, jj = cl & 31;
  #pragma unroll
  for (int v = 0; v < 4; ++v) {
    int i = mi*16 + kq*4 + v;              // center stripe
    float d2 = cnorm[p*32 + i] + nf - 2.f*acc[v];
    float t = tanhf(0.5f*sqrtf(fmaxf(d2, 1e-12f)));
    dm[((size_t)(p*8 + kidx) << 10) + ((size_t)i << 5) + jj] = t;
  }
}

// K4: anti-diagonal wavefront DP, 32 lanes per pair, 8 pairs per block.
// Covers inter (blocks 0..511) and intra (512..575) in one launch; dm buffers
// and output buffers are contiguous in the workspace.
__global__ __launch_bounds__(256) void k_dp(const float* __restrict__ dm,
                                            float* __restrict__ out) {
  __shared__ float tile[8*1024];
  int t = threadIdx.x;
  size_t base = (size_t)blockIdx.x * 8 * 1024;
  const float4v* src = (const float4v*)(dm + base);
  float4v* dst = (float4v*)tile;
  #pragma unroll
  for (int c2 = 0; c2 < 8; ++c2) dst[c2*256 + t] = src[c2*256 + t];
  __syncthreads();
  const float INF = __builtin_inff();
  int j  = t & 31;
  int pl = t >> 5;
  const float* mt = &tile[pl << 10];
  float A = INF;
  for (int d = 0; d < 63; ++d) {
    float left = __shfl_up(A, 1, 32);
    if (j == 0) left = INF;
    int i = d - j;
    int ii = i < 0 ? 0 : (i > 31 ? 31 : i);
    float dv = mt[(ii << 5) + j];
    float up = (i == 0) ? (j == 0 ? 0.f : INF) : A;
    A = (i >= 0 && i < 32) ? (fminf(up, left) + dv) : INF;
  }
  if (j == 31) out[(size_t)blockIdx.x*8 + pl] = A;
}

// K5: reductions + loss. out = [loss, intra_max[64], inter_min[64]]
__global__ __launch_bounds__(64) void k_final(const float* __restrict__ inter_full,
    const float* __restrict__ intra_pk, float* __restrict__ out) {
  int p = threadIdx.x;  // 0..63
  const float INF = __builtin_inff();
  float mn = INF;
  #pragma unroll 8
  for (int b = 0; b < 64; ++b)
    if (b != p) mn = fminf(mn, inter_full[p*64 + b]);
  float mx = -INF;
  #pragma unroll
  for (int k = 0; k < 8; ++k) mx = fmaxf(mx, intra_pk[p*8 + k]);
  out[1 + p]  = mx;
  out[65 + p] = mn;
  float v = fmaxf(mx - mn + 10.0f, 0.0f);
  #pragma unroll
  for (int off = 32; off > 0; off >>= 1) v += __shfl_down(v, off, 64);
  if (p == 0) out[0] = v * (1.0f/64.0f);
}

extern "C" void kernel_launch(void* const* d_in, const int* in_sizes, int n_in,
                              void* d_out, int out_size, void* d_ws, size_t ws_size,
                              hipStream_t stream) {
  const float* feat = (const float*)d_in[0];
  float* out = (float*)d_out;
  char* w = (char*)d_ws;
  // workspace layout (bytes)
  unsigned short* cbf      = (unsigned short*)w;            // 2048*2048*2 = 8,388,608
  float* cnorm             = (float*)(w + 8388608);         // 2048*4
  float* fnorm             = (float*)(w + 8396800);         // 16384*4
  float* dm_inter          = (float*)(w + 8462336);         // 4096*1024*4 = 16,777,216
  float* dm_intra          = (float*)(w + 25239552);        // 512*1024*4  =  2,097,152 (contiguous after dm_inter)
  float* inter_full        = (float*)(w + 27336704);        // 4096*4
  float* intra_pk          = (float*)(w + 27353088);        // 512*4 (contiguous after inter_full)
  // total 27,355,136 bytes

  k_centers<<<RR, 256, 0, stream>>>(feat, cbf, cnorm, fnorm);
  k_intra<<<PP*8, 256, 0, stream>>>(feat, cbf, cnorm, fnorm, dm_intra);  // right after centers: features L3-warm
  k_inter<<<256, 512, 0, stream>>>(cbf, cnorm, dm_inter);
  k_dp<<<576, 256, 0, stream>>>(dm_inter, inter_full);                    // covers inter + intra DP
  k_final<<<1, 64, 0, stream>>>(inter_full, intra_pk, out);
}

// Round 4
// 120.461 us; speedup vs baseline: 1.7317x; 1.1508x over previous
//
#include <hip/hip_runtime.h>
#include <cstdint>
#include <cstddef>

#define PP 64
#define KK 8
#define HH 32
#define DD 2048
#define RR (PP*HH)        // 2048 center rows

typedef __attribute__((ext_vector_type(4))) float  f32x4;
typedef __attribute__((ext_vector_type(4))) float  float4v;
typedef __attribute__((ext_vector_type(8))) short  short8;
typedef __attribute__((ext_vector_type(8))) __bf16 bf16x8;

__device__ __forceinline__ unsigned short f2bf(float f) {
  unsigned int u = __builtin_bit_cast(unsigned int, f);
  u += 0x7fffu + ((u >> 16) & 1u);
  return (unsigned short)(u >> 16);
}

__device__ __forceinline__ void gload_lds16(const void* g, void* l) {
  __builtin_amdgcn_global_load_lds(
      (const __attribute__((address_space(1))) void*)g,
      (__attribute__((address_space(3))) void*)l, 16, 0, 0);
}

// K1: centers (mean over K), bf16 cast of centers, center row norms, feature row norms.
__global__ __launch_bounds__(256) void k_centers(const float* __restrict__ feat,
    unsigned short* __restrict__ cbf, float* __restrict__ cnorm,
    float* __restrict__ fnorm) {
  int row = blockIdx.x;            // p*32 + h
  int p = row >> 5, h = row & 31;
  int tid = threadIdx.x;
  int d0 = tid * 8;
  float c[8];
  float red[9];
  #pragma unroll
  for (int e = 0; e < 8; ++e) c[e] = 0.f;
  #pragma unroll
  for (int k = 0; k < KK; ++k) {
    const float* src = feat + ((size_t)((p*KK + k)*HH + h))*DD + d0;
    float4v f0 = *(const float4v*)src;
    float4v f1 = *(const float4v*)(src + 4);
    float s = 0.f;
    #pragma unroll
    for (int e = 0; e < 4; ++e) {
      c[e]   += f0[e];
      c[4+e] += f1[e];
      s += f0[e]*f0[e] + f1[e]*f1[e];
    }
    red[k] = s;
  }
  float csq = 0.f;
  #pragma unroll
  for (int e = 0; e < 8; ++e) { c[e] *= 0.125f; csq += c[e]*c[e]; }
  unsigned int pk[4];
  #pragma unroll
  for (int e = 0; e < 4; ++e)
    pk[e] = (unsigned int)f2bf(c[2*e]) | ((unsigned int)f2bf(c[2*e+1]) << 16);
  *(uint4*)(cbf + (size_t)row*DD + d0) = make_uint4(pk[0], pk[1], pk[2], pk[3]);
  red[8] = csq;

  __shared__ float lred[4][9];
  int lane = tid & 63, wv = tid >> 6;
  #pragma unroll
  for (int r = 0; r < 9; ++r) {
    float v = red[r];
    #pragma unroll
    for (int off = 32; off > 0; off >>= 1) v += __shfl_down(v, off, 64);
    if (lane == 0) lred[wv][r] = v;
  }
  __syncthreads();
  if (tid < 9) {
    float s = lred[0][tid] + lred[1][tid] + lred[2][tid] + lred[3][tid];
    if (tid < 8) fnorm[((size_t)(p*KK + tid))*HH + h] = s;
    else         cnorm[row] = s;
  }
}

// K2: inter Gram, symmetric upper-tri only. 64x64 tiles over a 32x32 tile grid,
// 528 blocks (8*66, XCD-swizzled), 4 waves, BK=64, XOR-swizzled double-buffered LDS,
// 2-phase pipeline (stage next before compute, counted drain once per K-step).
// Writes dm only for pair a<b.
__global__ __launch_bounds__(256) void k_inter(const unsigned short* __restrict__ cbf,
    const float* __restrict__ cnorm, float* __restrict__ dm) {
  __shared__ unsigned short Ab[2][64*64];   // 2 x 8 KB
  __shared__ unsigned short Bb[2][64*64];   // 2 x 8 KB
  int tid = threadIdx.x;
  int lane = tid & 63, w = tid >> 6;        // 4 waves
  // XCD swizzle: 528 = 8 * 66
  int bid = (blockIdx.x & 7)*66 + (blockIdx.x >> 3);
  // upper-tri (incl diagonal) decode over 32x32 tile grid
  int tI = 0, rem = bid;
  while (rem >= 32 - tI) { rem -= 32 - tI; ++tI; }
  int tJ = tI + rem;
  int wr = w >> 1, wc = w & 1;
  int ln = lane & 15, kq = lane >> 4;
  f32x4 acc[2][2];
  #pragma unroll
  for (int a = 0; a < 2; ++a)
    #pragma unroll
    for (int b = 0; b < 2; ++b)
      #pragma unroll
      for (int e = 0; e < 4; ++e) acc[a][b][e] = 0.f;

  // staging: wave w stages A rows [w*16, w*16+16) and B rows likewise; 2 gloads each
  int sr = lane >> 3;                       // 0..7
  int sc = lane & 7;                        // physical 16B chunk
  int jch0 = sc ^ sr;                       // pre-swizzled logical chunk (row&7 == sr)
  const unsigned short* gA0 = cbf + (size_t)(tI*64 + w*16 + sr)*DD + jch0*8;
  const unsigned short* gB0 = cbf + (size_t)(tJ*64 + w*16 + sr)*DD + jch0*8;
  int lofs = w*1024 + lane*8;

  // fragment LDS element offsets: row*64 + ((ks*4+kq)^(ln&7))*8
  int aoff[2][2], boff[2][2];
  #pragma unroll
  for (int ks = 0; ks < 2; ++ks) {
    int phys = ((ks*4 + kq) ^ (ln & 7))*8;
    #pragma unroll
    for (int mt = 0; mt < 2; ++mt) {
      aoff[ks][mt] = (wr*32 + mt*16 + ln)*64 + phys;
      boff[ks][mt] = (wc*32 + mt*16 + ln)*64 + phys;
    }
  }

  // prologue: stage tile 0 into buffer 0
  gload_lds16(gA0,        &Ab[0][lofs]);
  gload_lds16(gA0 + 8*DD, &Ab[0][lofs + 512]);
  gload_lds16(gB0,        &Bb[0][lofs]);
  gload_lds16(gB0 + 8*DD, &Bb[0][lofs + 512]);
  asm volatile("s_waitcnt vmcnt(0)" ::: "memory");
  __builtin_amdgcn_s_barrier();

  int cur = 0;
  for (int t = 0; t < 32; ++t) {
    if (t < 31) {                           // stage next tile into other buffer
      int k0 = (t + 1) * 64;
      gload_lds16(gA0 + k0,        &Ab[cur^1][lofs]);
      gload_lds16(gA0 + 8*DD + k0, &Ab[cur^1][lofs + 512]);
      gload_lds16(gB0 + k0,        &Bb[cur^1][lofs]);
      gload_lds16(gB0 + 8*DD + k0, &Bb[cur^1][lofs + 512]);
    }
    #pragma unroll
    for (int ks = 0; ks < 2; ++ks) {
      bf16x8 af[2], bfr[2];
      #pragma unroll
      for (int mt = 0; mt < 2; ++mt) {
        af[mt]  = *(const bf16x8*)&Ab[cur][aoff[ks][mt]];
        bfr[mt] = *(const bf16x8*)&Bb[cur][boff[ks][mt]];
      }
      #pragma unroll
      for (int mt = 0; mt < 2; ++mt)
        #pragma unroll
        for (int nt = 0; nt < 2; ++nt)
          acc[mt][nt] = __builtin_amdgcn_mfma_f32_16x16x32_bf16(af[mt], bfr[nt], acc[mt][nt], 0, 0, 0);
    }
    asm volatile("s_waitcnt vmcnt(0)" ::: "memory");  // next tile staged
    __builtin_amdgcn_s_barrier();                      // all waves done reading cur
    cur ^= 1;
  }

  // epilogue: write only pairs a<b
  int a = tI*2 + wr, b = tJ*2 + wc;
  if (a < b) {
    #pragma unroll
    for (int mt = 0; mt < 2; ++mt) {
      #pragma unroll
      for (int nt = 0; nt < 2; ++nt) {
        int j  = nt*16 + ln;                 // 0..31 within pair
        int cc = tJ*64 + wc*32 + j;
        float nc = cnorm[cc];
        #pragma unroll
        for (int v = 0; v < 4; ++v) {
          int i  = mt*16 + kq*4 + v;         // 0..31 within pair
          int rr = tI*64 + wr*32 + i;
          float d2 = cnorm[rr] + nc - 2.f*acc[mt][nt][v];
          float t = tanhf(0.5f*sqrtf(fmaxf(d2, 1e-12f)));
          dm[(((size_t)a*64 + b) << 10) + ((size_t)i << 5) + j] = t;
        }
      }
    }
  }
}

// K3: intra distances. grid = P*8 blocks, 4 waves each, one 16x16 MFMA tile per wave.
// K streamed direct from global, manually unrolled x4 (12 loads in flight per wave).
__global__ __launch_bounds__(256) void k_intra(const float* __restrict__ feat,
    const unsigned short* __restrict__ cbf, const float* __restrict__ cnorm,
    const float* __restrict__ fnorm, float* __restrict__ dm) {
  int p  = blockIdx.x >> 3;
  int jb = blockIdx.x & 7;                 // 32-feature-row block
  int tid = threadIdx.x, lane = tid & 63, w = tid >> 6;
  int mi = w >> 1, ni = w & 1;
  int ln = lane & 15, kq = lane >> 4;
  f32x4 acc;
  #pragma unroll
  for (int e = 0; e < 4; ++e) acc[e] = 0.f;

  const unsigned short* ga = cbf + (size_t)(p*32 + mi*16 + ln)*DD + kq*8;
  const float* gb = feat + (size_t)(p*256 + jb*32 + ni*16 + ln)*DD + kq*8;

  for (int k0 = 0; k0 < DD; k0 += 128) {
    bf16x8 af[4];
    float4v f0[4], f1[4];
    #pragma unroll
    for (int u = 0; u < 4; ++u) {
      af[u] = *(const bf16x8*)(ga + k0 + u*32);
      f0[u] = *(const float4v*)(gb + k0 + u*32);
      f1[u] = *(const float4v*)(gb + k0 + u*32 + 4);
    }
    #pragma unroll
    for (int u = 0; u < 4; ++u) {
      unsigned int pk[4];
      #pragma unroll
      for (int e = 0; e < 2; ++e) {
        unsigned int a0 = __builtin_bit_cast(unsigned int, f0[u][2*e]);
        unsigned int a1 = __builtin_bit_cast(unsigned int, f0[u][2*e+1]);
        unsigned int b0 = __builtin_bit_cast(unsigned int, f1[u][2*e]);
        unsigned int b1 = __builtin_bit_cast(unsigned int, f1[u][2*e+1]);
        pk[e]   = (a0 >> 16) | (a1 & 0xffff0000u);   // truncated bf16 pair
        pk[2+e] = (b0 >> 16) | (b1 & 0xffff0000u);
      }
      bf16x8 bv = __builtin_bit_cast(bf16x8, pk);
      acc = __builtin_amdgcn_mfma_f32_16x16x32_bf16(af[u], bv, acc, 0, 0, 0);
    }
  }

  int cl = jb*32 + ni*16 + ln;             // feature index within class: k*32 + j
  float nf = fnorm[(size_t)p*256 + cl];
  int kidx = cl >> 5, jj = cl & 31;
  #pragma unroll
  for (int v = 0; v < 4; ++v) {
    int i = mi*16 + kq*4 + v;              // center stripe
    float d2 = cnorm[p*32 + i] + nf - 2.f*acc[v];
    float t = tanhf(0.5f*sqrtf(fmaxf(d2, 1e-12f)));
    dm[((size_t)(p*8 + kidx) << 10) + ((size_t)i << 5) + jj] = t;
  }
}

// K4: anti-diagonal wavefront DP, 32 lanes per pair, 8 pairs per block.
// Blocks 0..251: inter upper-tri pairs (2016), writes out[a*64+b] AND mirror.
// Blocks 252..315: intra pairs (512).
__global__ __launch_bounds__(256) void k_dp(const float* __restrict__ dm,
                                            float* __restrict__ outF) {
  __shared__ float tile[8*1024];
  int t = threadIdx.x;
  int pl = t >> 5, j32 = t & 31;
  int bi = blockIdx.x;
  size_t tbase;
  float *optr0, *optr1;
  if (bi < 252) {
    int q = bi*8 + pl;                     // 0..2015
    int a = 0, rem = q;
    while (rem >= 63 - a) { rem -= 63 - a; ++a; }
    int b = a + 1 + rem;
    tbase = ((size_t)a*64 + b) << 10;
    optr0 = outF + a*64 + b;
    optr1 = outF + b*64 + a;
  } else {
    int q = (bi - 252)*8 + pl;             // 0..511
    tbase = ((size_t)(4096 + q)) << 10;
    optr0 = outF + 4096 + q;
    optr1 = nullptr;
  }
  const float4v* src = (const float4v*)(dm + tbase);
  float4v* dst = (float4v*)&tile[pl << 10];
  #pragma unroll
  for (int r = 0; r < 8; ++r) dst[r*32 + j32] = src[r*32 + j32];
  __syncthreads();
  const float INF = __builtin_inff();
  const float* mt = &tile[pl << 10];
  float A = INF;
  for (int d = 0; d < 63; ++d) {
    float left = __shfl_up(A, 1, 32);
    if (j32 == 0) left = INF;
    int i = d - j32;
    int ii = i < 0 ? 0 : (i > 31 ? 31 : i);
    float dv = mt[(ii << 5) + j32];
    float up = (i == 0) ? (j32 == 0 ? 0.f : INF) : A;
    A = (i >= 0 && i < 32) ? (fminf(up, left) + dv) : INF;
  }
  if (j32 == 31) {
    *optr0 = A;
    if (optr1) *optr1 = A;
  }
}

// K5: reductions + loss. out = [loss, intra_max[64], inter_min[64]]
__global__ __launch_bounds__(64) void k_final(const float* __restrict__ inter_full,
    const float* __restrict__ intra_pk, float* __restrict__ out) {
  int p = threadIdx.x;  // 0..63
  const float INF = __builtin_inff();
  float mn = INF;
  #pragma unroll 8
  for (int b = 0; b < 64; ++b)
    if (b != p) mn = fminf(mn, inter_full[p*64 + b]);
  float mx = -INF;
  #pragma unroll
  for (int k = 0; k < 8; ++k) mx = fmaxf(mx, intra_pk[p*8 + k]);
  out[1 + p]  = mx;
  out[65 + p] = mn;
  float v = fmaxf(mx - mn + 10.0f, 0.0f);
  #pragma unroll
  for (int off = 32; off > 0; off >>= 1) v += __shfl_down(v, off, 64);
  if (p == 0) out[0] = v * (1.0f/64.0f);
}

extern "C" void kernel_launch(void* const* d_in, const int* in_sizes, int n_in,
                              void* d_out, int out_size, void* d_ws, size_t ws_size,
                              hipStream_t stream) {
  const float* feat = (const float*)d_in[0];
  float* out = (float*)d_out;
  char* w = (char*)d_ws;
  // workspace layout (bytes)
  unsigned short* cbf      = (unsigned short*)w;            // 2048*2048*2 = 8,388,608
  float* cnorm             = (float*)(w + 8388608);         // 2048*4
  float* fnorm             = (float*)(w + 8396800);         // 16384*4
  float* dm_all            = (float*)(w + 8462336);         // (4096+512)*1024*4 = 18,874,368
  float* inter_full        = (float*)(w + 27336704);        // 4096*4
  float* intra_pk          = (float*)(w + 27353088);        // 512*4 (contiguous after inter_full)
  float* dm_intra          = dm_all + 4096*1024;
  // total 27,355,136 bytes

  k_centers<<<RR, 256, 0, stream>>>(feat, cbf, cnorm, fnorm);
  k_intra<<<PP*8, 256, 0, stream>>>(feat, cbf, cnorm, fnorm, dm_intra);  // features L3-warm
  k_inter<<<528, 256, 0, stream>>>(cbf, cnorm, dm_all);
  k_dp<<<316, 256, 0, stream>>>(dm_all, inter_full);                      // inter pairs + intra
  k_final<<<1, 64, 0, stream>>>(inter_full, intra_pk, out);
}

// Round 5
// 101.094 us; speedup vs baseline: 2.0634x; 1.1916x over previous
//
#include <hip/hip_runtime.h>
#include <cstdint>
#include <cstddef>

#define PP 64
#define KK 8
#define HH 32
#define DD 2048
#define RR (PP*HH)        // 2048 center rows

typedef __attribute__((ext_vector_type(4))) float  f32x4;
typedef __attribute__((ext_vector_type(4))) float  float4v;
typedef __attribute__((ext_vector_type(8))) __bf16 bf16x8;

__device__ __forceinline__ unsigned short f2bf(float f) {
  unsigned int u = __builtin_bit_cast(unsigned int, f);
  u += 0x7fffu + ((u >> 16) & 1u);
  return (unsigned short)(u >> 16);
}

__device__ __forceinline__ void gload_lds16(const void* g, void* l) {
  __builtin_amdgcn_global_load_lds(
      (const __attribute__((address_space(1))) void*)g,
      (__attribute__((address_space(3))) void*)l, 16, 0, 0);
}

// K1: centers (mean over K), bf16 centers, bf16 feature copy, row norms.
__global__ __launch_bounds__(256) void k_centers(const float* __restrict__ feat,
    unsigned short* __restrict__ cbf, unsigned short* __restrict__ fbf,
    float* __restrict__ cnorm, float* __restrict__ fnorm) {
  int row = blockIdx.x;            // p*32 + h
  int p = row >> 5, h = row & 31;
  int tid = threadIdx.x;
  int d0 = tid * 8;
  float c[8];
  float red[9];
  #pragma unroll
  for (int e = 0; e < 8; ++e) c[e] = 0.f;
  #pragma unroll
  for (int k = 0; k < KK; ++k) {
    size_t frow = (size_t)((p*KK + k)*HH + h);
    const float* src = feat + frow*DD + d0;
    float4v f0 = *(const float4v*)src;
    float4v f1 = *(const float4v*)(src + 4);
    float s = 0.f;
    #pragma unroll
    for (int e = 0; e < 4; ++e) {
      c[e]   += f0[e];
      c[4+e] += f1[e];
      s += f0[e]*f0[e] + f1[e]*f1[e];
    }
    red[k] = s;
    unsigned int fk[4];
    #pragma unroll
    for (int e = 0; e < 2; ++e) {
      fk[e]   = (unsigned int)f2bf(f0[2*e]) | ((unsigned int)f2bf(f0[2*e+1]) << 16);
      fk[2+e] = (unsigned int)f2bf(f1[2*e]) | ((unsigned int)f2bf(f1[2*e+1]) << 16);
    }
    *(uint4*)(fbf + frow*DD + d0) = make_uint4(fk[0], fk[1], fk[2], fk[3]);
  }
  float csq = 0.f;
  #pragma unroll
  for (int e = 0; e < 8; ++e) { c[e] *= 0.125f; csq += c[e]*c[e]; }
  unsigned int pk[4];
  #pragma unroll
  for (int e = 0; e < 4; ++e)
    pk[e] = (unsigned int)f2bf(c[2*e]) | ((unsigned int)f2bf(c[2*e+1]) << 16);
  *(uint4*)(cbf + (size_t)row*DD + d0) = make_uint4(pk[0], pk[1], pk[2], pk[3]);
  red[8] = csq;

  __shared__ float lred[4][9];
  int lane = tid & 63, wv = tid >> 6;
  #pragma unroll
  for (int r = 0; r < 9; ++r) {
    float v = red[r];
    #pragma unroll
    for (int off = 32; off > 0; off >>= 1) v += __shfl_down(v, off, 64);
    if (lane == 0) lred[wv][r] = v;
  }
  __syncthreads();
  if (tid < 9) {
    float s = lred[0][tid] + lred[1][tid] + lred[2][tid] + lred[3][tid];
    if (tid < 8) fnorm[((size_t)(p*KK + tid))*HH + h] = s;
    else         cnorm[row] = s;
  }
}

// K2: inter Gram, symmetric upper-tri only. 64x64 tiles over 32x32 tile grid,
// 528 blocks (8*66 XCD-swizzled), 4 waves, BK=64, XOR-swizzled dbuf LDS,
// 2-phase pipeline. Writes dm only for pair a<b.
__global__ __launch_bounds__(256) void k_inter(const unsigned short* __restrict__ cbf,
    const float* __restrict__ cnorm, float* __restrict__ dm) {
  __shared__ unsigned short Ab[2][64*64];
  __shared__ unsigned short Bb[2][64*64];
  int tid = threadIdx.x;
  int lane = tid & 63, w = tid >> 6;
  int bid = (blockIdx.x & 7)*66 + (blockIdx.x >> 3);
  int tI = 0, rem = bid;
  while (rem >= 32 - tI) { rem -= 32 - tI; ++tI; }
  int tJ = tI + rem;
  int wr = w >> 1, wc = w & 1;
  int ln = lane & 15, kq = lane >> 4;
  f32x4 acc[2][2];
  #pragma unroll
  for (int a = 0; a < 2; ++a)
    #pragma unroll
    for (int b = 0; b < 2; ++b)
      #pragma unroll
      for (int e = 0; e < 4; ++e) acc[a][b][e] = 0.f;

  int sr = lane >> 3, sc = lane & 7;
  int jch0 = sc ^ sr;
  const unsigned short* gA0 = cbf + (size_t)(tI*64 + w*16 + sr)*DD + jch0*8;
  const unsigned short* gB0 = cbf + (size_t)(tJ*64 + w*16 + sr)*DD + jch0*8;
  int lofs = w*1024 + lane*8;

  int aoff[2][2], boff[2][2];
  #pragma unroll
  for (int ks = 0; ks < 2; ++ks) {
    int phys = ((ks*4 + kq) ^ (ln & 7))*8;
    #pragma unroll
    for (int mt = 0; mt < 2; ++mt) {
      aoff[ks][mt] = (wr*32 + mt*16 + ln)*64 + phys;
      boff[ks][mt] = (wc*32 + mt*16 + ln)*64 + phys;
    }
  }

  gload_lds16(gA0,        &Ab[0][lofs]);
  gload_lds16(gA0 + 8*DD, &Ab[0][lofs + 512]);
  gload_lds16(gB0,        &Bb[0][lofs]);
  gload_lds16(gB0 + 8*DD, &Bb[0][lofs + 512]);
  asm volatile("s_waitcnt vmcnt(0)" ::: "memory");
  __builtin_amdgcn_s_barrier();

  int cur = 0;
  for (int t = 0; t < 32; ++t) {
    if (t < 31) {
      int k0 = (t + 1) * 64;
      gload_lds16(gA0 + k0,        &Ab[cur^1][lofs]);
      gload_lds16(gA0 + 8*DD + k0, &Ab[cur^1][lofs + 512]);
      gload_lds16(gB0 + k0,        &Bb[cur^1][lofs]);
      gload_lds16(gB0 + 8*DD + k0, &Bb[cur^1][lofs + 512]);
    }
    #pragma unroll
    for (int ks = 0; ks < 2; ++ks) {
      bf16x8 af[2], bfr[2];
      #pragma unroll
      for (int mt = 0; mt < 2; ++mt) {
        af[mt]  = *(const bf16x8*)&Ab[cur][aoff[ks][mt]];
        bfr[mt] = *(const bf16x8*)&Bb[cur][boff[ks][mt]];
      }
      #pragma unroll
      for (int mt = 0; mt < 2; ++mt)
        #pragma unroll
        for (int nt = 0; nt < 2; ++nt)
          acc[mt][nt] = __builtin_amdgcn_mfma_f32_16x16x32_bf16(af[mt], bfr[nt], acc[mt][nt], 0, 0, 0);
    }
    asm volatile("s_waitcnt vmcnt(0)" ::: "memory");
    __builtin_amdgcn_s_barrier();
    cur ^= 1;
  }

  int a = tI*2 + wr, b = tJ*2 + wc;
  if (a < b) {
    #pragma unroll
    for (int mt = 0; mt < 2; ++mt) {
      #pragma unroll
      for (int nt = 0; nt < 2; ++nt) {
        int j  = nt*16 + ln;
        int cc = tJ*64 + wc*32 + j;
        float nc = cnorm[cc];
        #pragma unroll
        for (int v = 0; v < 4; ++v) {
          int i  = mt*16 + kq*4 + v;
          int rr = tI*64 + wr*32 + i;
          float d2 = cnorm[rr] + nc - 2.f*acc[mt][nt][v];
          float t = tanhf(0.5f*sqrtf(fmaxf(d2, 1e-12f)));
          dm[(((size_t)a*64 + b) << 10) + ((size_t)i << 5) + j] = t;
        }
      }
    }
  }
}

// K3: intra. 512 blocks (class p = bid>>3, feature block jb = bid&7: 32 rows).
// 4 waves = (ks = w>>1 K-split, nt = w&1 feature half). A = centers 32 rows (bf16),
// B = features 32 rows (bf16), BK=64, XOR-swizzled dbuf LDS, 2-phase pipeline,
// LDS K-split reduce, fused tanh epilogue. Features read ONCE via gload_lds.
__global__ __launch_bounds__(256) void k_intra(const unsigned short* __restrict__ fbf,
    const unsigned short* __restrict__ cbf, const float* __restrict__ cnorm,
    const float* __restrict__ fnorm, float* __restrict__ dm) {
  __shared__ unsigned short Ab[2][32*64];   // centers tile, 4 KB per buf
  __shared__ unsigned short Bb[2][32*64];   // features tile
  int tid = threadIdx.x, lane = tid & 63, w = tid >> 6;
  int p = blockIdx.x >> 3, jb = blockIdx.x & 7;
  int ks = w >> 1, nt = w & 1;
  int ln = lane & 15, kq = lane >> 4;
  f32x4 acc[2];
  #pragma unroll
  for (int mi = 0; mi < 2; ++mi)
    #pragma unroll
    for (int e = 0; e < 4; ++e) acc[mi][e] = 0.f;

  // staging: waves 0,1 stage A rows [ (w&1)*16, +16 ); waves 2,3 stage B likewise
  int sr = lane >> 3, sc = lane & 7;
  int jch0 = sc ^ sr;                       // pre-swizzled global chunk
  int hw = w & 1;
  const unsigned short* g0 = (w < 2)
      ? cbf + (size_t)(p*32 + hw*16 + sr)*DD + jch0*8
      : fbf + (size_t)(p*256 + jb*32 + hw*16 + sr)*DD + jch0*8;
  int lofs = hw*1024 + lane*8;
  unsigned short* base[2];
  base[0] = (w < 2) ? &Ab[0][lofs] : &Bb[0][lofs];
  base[1] = (w < 2) ? &Ab[1][lofs] : &Bb[1][lofs];

  // fragment offsets: phys chunk = (ks*4+kq) ^ (ln&7)
  int phys = ((ks*4 + kq) ^ (ln & 7))*8;
  int aoff[2];
  #pragma unroll
  for (int mi = 0; mi < 2; ++mi) aoff[mi] = (mi*16 + ln)*64 + phys;
  int boff = (nt*16 + ln)*64 + phys;

  gload_lds16(g0,        base[0]);
  gload_lds16(g0 + 8*DD, base[0] + 512);
  asm volatile("s_waitcnt vmcnt(0)" ::: "memory");
  __builtin_amdgcn_s_barrier();

  int cur = 0;
  for (int t = 0; t < 32; ++t) {
    if (t < 31) {
      int k0 = (t + 1) * 64;
      gload_lds16(g0 + k0,        base[cur^1]);
      gload_lds16(g0 + 8*DD + k0, base[cur^1] + 512);
    }
    bf16x8 bfr = *(const bf16x8*)&Bb[cur][boff];
    #pragma unroll
    for (int mi = 0; mi < 2; ++mi) {
      bf16x8 af = *(const bf16x8*)&Ab[cur][aoff[mi]];
      acc[mi] = __builtin_amdgcn_mfma_f32_16x16x32_bf16(af, bfr, acc[mi], 0, 0, 0);
    }
    asm volatile("s_waitcnt vmcnt(0)" ::: "memory");
    __builtin_amdgcn_s_barrier();
    cur ^= 1;
  }

  // K-split reduce: waves 2,3 -> waves 0,1 (matched nt)
  float* fb = (float*)Ab;                   // 4096 floats available
  __syncthreads();
  if (w >= 2) {
    #pragma unroll
    for (int mi = 0; mi < 2; ++mi)
      *(f32x4*)(fb + ((w - 2)*2 + mi)*256 + lane*4) = acc[mi];
  }
  __syncthreads();
  if (w < 2) {
    #pragma unroll
    for (int mi = 0; mi < 2; ++mi)
      acc[mi] += *(const f32x4*)(fb + (w*2 + mi)*256 + lane*4);
    int cl = jb*32 + nt*16 + ln;            // feature index within class
    float nf = fnorm[(size_t)p*256 + cl];
    #pragma unroll
    for (int mi = 0; mi < 2; ++mi) {
      #pragma unroll
      for (int v = 0; v < 4; ++v) {
        int i = mi*16 + kq*4 + v;           // center stripe 0..31
        float d2 = cnorm[p*32 + i] + nf - 2.f*acc[mi][v];
        float t = tanhf(0.5f*sqrtf(fmaxf(d2, 1e-12f)));
        dm[((size_t)(p*8 + jb) << 10) + ((size_t)i << 5) + (nt*16 + ln)] = t;
      }
    }
  }
}

// K4: anti-diagonal wavefront DP, 32 lanes per pair, 8 pairs per block.
// Blocks 0..251: inter upper-tri pairs (2016) with mirror write; 252..315: intra.
__global__ __launch_bounds__(256) void k_dp(const float* __restrict__ dm,
                                            float* __restrict__ outF) {
  __shared__ float tile[8*1024];
  int t = threadIdx.x;
  int pl = t >> 5, j32 = t & 31;
  int bi = blockIdx.x;
  size_t tbase;
  float *optr0, *optr1;
  if (bi < 252) {
    int q = bi*8 + pl;
    int a = 0, rem = q;
    while (rem >= 63 - a) { rem -= 63 - a; ++a; }
    int b = a + 1 + rem;
    tbase = ((size_t)a*64 + b) << 10;
    optr0 = outF + a*64 + b;
    optr1 = outF + b*64 + a;
  } else {
    int q = (bi - 252)*8 + pl;
    tbase = ((size_t)(4096 + q)) << 10;
    optr0 = outF + 4096 + q;
    optr1 = nullptr;
  }
  const float4v* src = (const float4v*)(dm + tbase);
  float4v* dst = (float4v*)&tile[pl << 10];
  #pragma unroll
  for (int r = 0; r < 8; ++r) dst[r*32 + j32] = src[r*32 + j32];
  __syncthreads();
  const float INF = __builtin_inff();
  const float* mt = &tile[pl << 10];
  float A = INF;
  for (int d = 0; d < 63; ++d) {
    float left = __shfl_up(A, 1, 32);
    if (j32 == 0) left = INF;
    int i = d - j32;
    int ii = i < 0 ? 0 : (i > 31 ? 31 : i);
    float dv = mt[(ii << 5) + j32];
    float up = (i == 0) ? (j32 == 0 ? 0.f : INF) : A;
    A = (i >= 0 && i < 32) ? (fminf(up, left) + dv) : INF;
  }
  if (j32 == 31) {
    *optr0 = A;
    if (optr1) *optr1 = A;
  }
}

// K5: reductions + loss. out = [loss, intra_max[64], inter_min[64]]
__global__ __launch_bounds__(64) void k_final(const float* __restrict__ inter_full,
    const float* __restrict__ intra_pk, float* __restrict__ out) {
  int p = threadIdx.x;
  const float INF = __builtin_inff();
  float mn = INF;
  #pragma unroll 8
  for (int b = 0; b < 64; ++b)
    if (b != p) mn = fminf(mn, inter_full[p*64 + b]);
  float mx = -INF;
  #pragma unroll
  for (int k = 0; k < 8; ++k) mx = fmaxf(mx, intra_pk[p*8 + k]);
  out[1 + p]  = mx;
  out[65 + p] = mn;
  float v = fmaxf(mx - mn + 10.0f, 0.0f);
  #pragma unroll
  for (int off = 32; off > 0; off >>= 1) v += __shfl_down(v, off, 64);
  if (p == 0) out[0] = v * (1.0f/64.0f);
}

extern "C" void kernel_launch(void* const* d_in, const int* in_sizes, int n_in,
                              void* d_out, int out_size, void* d_ws, size_t ws_size,
                              hipStream_t stream) {
  const float* feat = (const float*)d_in[0];
  float* out = (float*)d_out;
  char* w = (char*)d_ws;
  // workspace layout (bytes)
  unsigned short* cbf = (unsigned short*)w;                 // 8,388,608
  unsigned short* fbf = (unsigned short*)(w + 8388608);     // 67,108,864
  float* cnorm        = (float*)(w + 75497472);             // 8,192
  float* fnorm        = (float*)(w + 75505664);             // 65,536
  float* dm_all       = (float*)(w + 75571200);             // 18,874,368
  float* inter_full   = (float*)(w + 94445568);             // 16,384
  float* intra_pk     = (float*)(w + 94461952);             // 2,048
  float* dm_intra     = dm_all + 4096*1024;
  // total ~94.5 MB

  k_centers<<<RR, 256, 0, stream>>>(feat, cbf, fbf, cnorm, fnorm);
  k_intra<<<PP*8, 256, 0, stream>>>(fbf, cbf, cnorm, fnorm, dm_intra);  // fbf L3-warm
  k_inter<<<528, 256, 0, stream>>>(cbf, cnorm, dm_all);
  k_dp<<<316, 256, 0, stream>>>(dm_all, inter_full);
  k_final<<<1, 64, 0, stream>>>(inter_full, intra_pk, out);
}